// Round 22
// baseline (133.723 us; speedup 1.0000x reference)
//
#include <hip/hip_runtime.h>
#include <cstdint>
#include <cstddef>

#define S 8192
#define Dm 1024
#define E 64
#define CAP 128
#define SEC 67108864ull   // S*E*CAP
// out layout (float32 elements), out_size = 1 + 2*SEC + 64 = 134,217,793:
//   [0] l_aux | [1,1+SEC) combine | [1+SEC,1+2SEC) dispatch | [1+2SEC,+64) counts
// Coverage map (every element written every call):
//   K1 fill: elements [1+SEC+3, 134217792) zeroed via chunks [16777217,33554448)
//            + scalar zeros at out[1+SEC],out[2+SEC],out[3+SEC]; la_ws zeroed
//   K2: counts[0..63] written unconditionally (incl. element 134217792)
//   K3: combine elements [1, 1+SEC) = final values; dispatch 1.0s; out[0]=l_aux

#define GEMM_BLOCKS 512   // 16 tokens x 64 experts each -> 2 GEMM blocks/CU
#define FILL_BLOCKS 1536
#define B0 16777217u      // first aligned chunk of the dispatch-half fill
#define CH 10923u         // ceil(16777231 / FILL_BLOCKS)
#define N4END 33554448u
#define WSCALE 4096.0f
#define INV_WSCALE (1.0f / 4096.0f)

typedef float f32x4 __attribute__((ext_vector_type(4)));
typedef _Float16 f16x4 __attribute__((ext_vector_type(4)));
typedef _Float16 f16x8 __attribute__((ext_vector_type(8)));

#define CV4(H, L, ROW, COL, V, SCALE) do {                                     \
    f16x4 hh, ll; float t_;                                                    \
    t_ = (V).x * (SCALE); hh[0] = (_Float16)t_; ll[0] = (_Float16)(t_ - (float)hh[0]); \
    t_ = (V).y * (SCALE); hh[1] = (_Float16)t_; ll[1] = (_Float16)(t_ - (float)hh[1]); \
    t_ = (V).z * (SCALE); hh[2] = (_Float16)t_; ll[2] = (_Float16)(t_ - (float)hh[2]); \
    t_ = (V).w * (SCALE); hh[3] = (_Float16)t_; ll[3] = (_Float16)(t_ - (float)hh[3]); \
    *(f16x4*)&H[ROW][COL] = hh;                                                \
    *(f16x4*)&L[ROW][COL] = ll;                                                \
} while (0)

// ---------------- K1: MFMA GEMM (2 blocks/CU) + dispatch-half fill -----------
// R21 structure, ONE change: GEMM split into 512 blocks of 16 tokens x 256
// threads (27.5 KB LDS -> 2 independent barrier-domains per CU). While one
// block waits on its staging loads/barrier, the other computes — the classic
// occupancy fix, never before applied to the GEMM (always 1 block/CU).
__global__ __launch_bounds__(256) void k_main(const float* __restrict__ x,
                                              const float* __restrict__ w,
                                              float* __restrict__ gate,
                                              int* __restrict__ idx,
                                              float* __restrict__ me_part,
                                              int* __restrict__ cnt_g,
                                              float* __restrict__ la_ws,
                                              float* __restrict__ out) {
    int bid = blockIdx.x;
    int tid = threadIdx.x;
    if (bid < GEMM_BLOCKS) {
        __shared__ _Float16 Ah[16][72];    // 2.3 KB
        __shared__ _Float16 Alo[16][72];   // 2.3 KB
        __shared__ _Float16 Wh[64][72];    // 9.2 KB
        __shared__ _Float16 Wlo[64][72];   // 9.2 KB
        __shared__ float Sl[16][66];       // 4.2 KB
        __shared__ float sm[16];
        __shared__ float sinv[16];
        __shared__ int sidx[16];
        int t0 = bid * 16;
        // staging maps: A 16x64 (1 float4/thread); W 64x64 (4 float4/thread,
        // load j covers rows j*16..j*16+15, lanes 0-15 contiguous in a row)
        int ar = tid >> 4;                 // 0..15
        int ac = (tid & 15) * 4;
        const float* asrc = x + (size_t)(t0 + ar) * Dm + ac;
        const float* wsrc = w + (size_t)(tid >> 4) * Dm + (tid & 15) * 4;

        // MFMA split: wave wv = n-tile (16 experts); m-tile single (16 tokens)
        int wv = tid >> 6;
        int l = tid & 63;
        int lr = l & 15;
        int lg = l >> 4;
        f32x4 acc = {0.f, 0.f, 0.f, 0.f};

        // 2-deep prefetch: p = even chunks, q = odd
        float4 pa, pw0, pw1, pw2, pw3;
        float4 qa, qw0, qw1, qw2, qw3;
#define LOADP(KB)                                                              \
        pa = *(const float4*)(asrc + (KB));                                    \
        pw0 = *(const float4*)(wsrc + (KB));                                   \
        pw1 = *(const float4*)(wsrc + 16 * (size_t)Dm + (KB));                 \
        pw2 = *(const float4*)(wsrc + 32 * (size_t)Dm + (KB));                 \
        pw3 = *(const float4*)(wsrc + 48 * (size_t)Dm + (KB));
#define LOADQ(KB)                                                              \
        qa = *(const float4*)(asrc + (KB));                                    \
        qw0 = *(const float4*)(wsrc + (KB));                                   \
        qw1 = *(const float4*)(wsrc + 16 * (size_t)Dm + (KB));                 \
        qw2 = *(const float4*)(wsrc + 32 * (size_t)Dm + (KB));                 \
        qw3 = *(const float4*)(wsrc + 48 * (size_t)Dm + (KB));
#define WRITE_LDS(A, W0, W1, W2, W3)                                           \
        CV4(Ah, Alo, ar, ac, A, 1.0f);                                         \
        CV4(Wh, Wlo, (tid >> 4), ((tid & 15) * 4), W0, WSCALE);                \
        CV4(Wh, Wlo, (16 + (tid >> 4)), ((tid & 15) * 4), W1, WSCALE);         \
        CV4(Wh, Wlo, (32 + (tid >> 4)), ((tid & 15) * 4), W2, WSCALE);         \
        CV4(Wh, Wlo, (48 + (tid >> 4)), ((tid & 15) * 4), W3, WSCALE);
#define INNER_MFMA                                                             \
        _Pragma("unroll")                                                      \
        for (int ks = 0; ks < 2; ++ks) {                                       \
            int kc = ks * 32 + lg * 8;                                         \
            f16x8 ah = *(const f16x8*)&Ah[lr][kc];                             \
            f16x8 al = *(const f16x8*)&Alo[lr][kc];                            \
            f16x8 bh = *(const f16x8*)&Wh[wv * 16 + lr][kc];                   \
            f16x8 bl = *(const f16x8*)&Wlo[wv * 16 + lr][kc];                  \
            acc = __builtin_amdgcn_mfma_f32_16x16x32_f16(ah, bh, acc, 0, 0, 0); \
            acc = __builtin_amdgcn_mfma_f32_16x16x32_f16(al, bh, acc, 0, 0, 0); \
            acc = __builtin_amdgcn_mfma_f32_16x16x32_f16(ah, bl, acc, 0, 0, 0); \
        }

        LOADP(0)
        LOADQ(64)
        for (int ch = 0; ch < 16; ch += 2) {
            // even chunk: write p -> LDS, refill p (ch+2), compute
            __syncthreads();
            WRITE_LDS(pa, pw0, pw1, pw2, pw3)
            __syncthreads();
            if (ch + 2 < 16) { LOADP((ch + 2) * 64) }
            INNER_MFMA
            // odd chunk: write q -> LDS, refill q (ch+3), compute
            __syncthreads();
            WRITE_LDS(qa, qw0, qw1, qw2, qw3)
            __syncthreads();
            if (ch + 3 < 16) { LOADQ((ch + 3) * 64) }
            INNER_MFMA
        }
#undef LOADP
#undef LOADQ
#undef WRITE_LDS
#undef INNER_MFMA
        __syncthreads();
        // D -> Sl (R16/R17-verified C/D layout: row = lg*4 + r, col = lr)
#pragma unroll
        for (int r = 0; r < 4; ++r)
            Sl[lg * 4 + r][wv * 16 + lr] = acc[r] * INV_WSCALE;
        __syncthreads();
        if (tid < 16) {   // row phase: first-index argmax + exp-sum
            float m = Sl[tid][0];
            int am = 0;
#pragma unroll
            for (int c = 1; c < E; ++c) {
                float v = Sl[tid][c];
                if (v > m) { m = v; am = c; }
            }
            float ssum = 0.f;
#pragma unroll
            for (int c = 0; c < E; ++c) ssum += __expf(Sl[tid][c] - m);
            float inv = 1.0f / ssum;
            gate[t0 + tid] = inv;
            idx[t0 + tid] = am;
            sm[tid] = m;
            sinv[tid] = inv;
            sidx[tid] = am;
        }
        __syncthreads();
        if (tid < E) {    // column phase: me partials + exact expert histogram
            float cs = 0.f;
            int cnt = 0;
#pragma unroll
            for (int r = 0; r < 16; ++r) {
                cs += __expf(Sl[r][tid] - sm[r]) * sinv[r];
                cnt += (sidx[r] == tid) ? 1 : 0;
            }
            me_part[bid * E + tid] = cs;
            cnt_g[bid * E + tid] = cnt;
        }
    } else {
        // block-chunked zero-fill of dispatch half + counts[0..62]
        int fb = bid - GEMM_BLOCKS;
        if (fb == 0 && tid == 0) {
            out[1 + SEC] = 0.f; out[2 + SEC] = 0.f; out[3 + SEC] = 0.f;
            la_ws[0] = 0.f;
        }
        unsigned base = B0 + (unsigned)fb * CH;
        f32x4 z = {0.f, 0.f, 0.f, 0.f};
        f32x4* o4 = (f32x4*)out;
        for (unsigned j = tid; j < CH; j += 256u) {
            unsigned i = base + j;
            if (i < N4END) o4[i] = z;
        }
    }
}

// ---------------- K2: quartered scan -> tg[], counts, l_aux accum ------------
// R20/R21's proven quartered ballot scan; adjusted to 512 GEMM blocks
// (quarter q seeds from cnt_g over blocks [0, 128q)).
__global__ __launch_bounds__(256) void k_scan(const int* __restrict__ idx,
                                              const float* __restrict__ gate,
                                              const float* __restrict__ me_part,
                                              const int* __restrict__ cnt_g,
                                              float2* __restrict__ tg,
                                              float* __restrict__ la_ws,
                                              float* __restrict__ out) {
    int e = blockIdx.x >> 2;
    int q = blockIdx.x & 3;
    int tid = threadIdx.x;
    int lane = tid & 63;
    int wid = tid >> 6;
    __shared__ int wsum[4];
    __shared__ int ired[256];
    __shared__ float red[256];
    int nb = q << 7;                   // GEMM blocks before this quarter
    int a = 0;
    for (int b = tid; b < nb; b += 256) a += cnt_g[b * E + e];
    ired[tid] = a;
    __syncthreads();
    for (int s2 = 128; s2 > 0; s2 >>= 1) {
        if (tid < s2) ired[tid] += ired[tid + s2];
        __syncthreads();
    }
    int running = ired[0];
    __syncthreads();
    for (int ch = 0; ch < 8; ++ch) {
        int t = q * 2048 + ch * 256 + tid;
        bool f = (idx[t] == e);
        unsigned long long b = __ballot(f);
        int pre = __popcll(b & ((1ull << lane) - 1ull));
        if (lane == 0) wsum[wid] = __popcll(b);
        __syncthreads();
        int off = running;
#pragma unroll
        for (int w2 = 0; w2 < 4; ++w2)
            if (w2 < wid) off += wsum[w2];
        int p = off + pre;
        if (f) {   // every token written exactly once (by its argmax expert)
            int tgt = (p < CAP) ? e * CAP + p : -1;
            tg[t] = make_float2(__int_as_float(tgt), gate[t]);
        }
        running += wsum[0] + wsum[1] + wsum[2] + wsum[3];
        __syncthreads();
    }
    if (q == 3) {
        red[tid] = me_part[tid * E + e] + me_part[(tid + 256) * E + e];
        __syncthreads();
        for (int s2 = 128; s2 > 0; s2 >>= 1) {
            if (tid < s2) red[tid] += red[tid + s2];
            __syncthreads();
        }
        if (tid == 0) {
            out[1 + 2 * (size_t)SEC + e] = (float)running;   // exp_counts
            float la = red[0] * (1.0f / (float)S) *
                       ((float)running / (float)S) * (float)E;
            atomicAdd(la_ws, la);
        }
    }
}

// ---------------- K3: merge-fill combine half + dispatch ones + l_aux --------
// R21's proven pure-write merge kernel, verbatim.
__global__ __launch_bounds__(256) void k_merge(const float2* __restrict__ tg,
                                               const float* __restrict__ la_ws,
                                               float* __restrict__ out) {
    int bid = blockIdx.x;
    int tid = threadIdx.x;
    if (bid == 0 && tid == 0) out[0] = la_ws[0];   // l_aux (K2 complete)
    f32x4* o4 = (f32x4*)out;
#pragma unroll
    for (int k = 0; k < 4; ++k) {
        int t = bid * 4 + k;
        float2 g = tg[t];
        int tgt = __float_as_int(g.x);     // local slot in [0,8192) or -1
        float gv = g.y;
        for (int j = 1 + tid; j < 2048; j += 256) {
            int base = 4 * j - 1;
            f32x4 v;
            v[0] = (tgt == base) ? gv : 0.f;
            v[1] = (tgt == base + 1) ? gv : 0.f;
            v[2] = (tgt == base + 2) ? gv : 0.f;
            v[3] = (tgt == base + 3) ? gv : 0.f;
            o4[2048u * (unsigned)t + (unsigned)j] = v;
        }
        if (tid < 4) {   // boundary scalars: local c = 0,1,2,8191
            int c = (tid < 3) ? tid : 8191;
            out[1 + (size_t)t * 8192 + c] = (tgt == c) ? gv : 0.f;
        }
        if (tid == 4 && tgt >= 0)   // dispatch one (half zeroed by K1)
            out[1 + SEC + (size_t)t * 8192 + tgt] = 1.0f;
    }
}

extern "C" void kernel_launch(void* const* d_in, const int* in_sizes, int n_in,
                              void* d_out, int out_size, void* d_ws, size_t ws_size,
                              hipStream_t stream) {
    const float* x = (const float*)d_in[0];      // [S, Dm] fp32
    const float* w = (const float*)d_in[1];      // [E, Dm] fp32
    float* out = (float*)d_out;

    // ws layout
    float* me_part = (float*)d_ws;               // [512][64] = 128 KB
    float* gate = me_part + GEMM_BLOCKS * E;     // S floats
    int* idx = (int*)(gate + S);                 // S ints
    int* cnt_g = idx + S;                        // [512][64] = 128 KB
    float2* tg = (float2*)(cnt_g + GEMM_BLOCKS * E);   // S float2 = 64 KB
    float* la_ws = (float*)(tg + S);             // 1 float

    k_main<<<dim3(GEMM_BLOCKS + FILL_BLOCKS), dim3(256), 0, stream>>>(
        x, w, gate, idx, me_part, cnt_g, la_ws, out);
    k_scan<<<dim3(256), dim3(256), 0, stream>>>(
        idx, gate, me_part, cnt_g, tg, la_ws, out);
    k_merge<<<dim3(2048), dim3(256), 0, stream>>>(tg, la_ws, out);
}

// Round 23
// 130.897 us; speedup vs baseline: 1.0216x; 1.0216x over previous
//
#include <hip/hip_runtime.h>
#include <cstdint>
#include <cstddef>

#define S 8192
#define Dm 1024
#define E 64
#define CAP 128
#define SEC 67108864ull   // S*E*CAP
// out layout (float32 elements), out_size = 1 + 2*SEC + 64 = 134,217,793:
//   [0] l_aux | [1,1+SEC) combine | [1+SEC,1+2SEC) dispatch | [1+2SEC,+64) counts
// Coverage map (every element written every call):
//   K1 fill: elements [1+SEC+3, 134217792) zeroed via chunks [16777217,33554448)
//            + scalar zeros at out[1+SEC..3+SEC]; la_ws zeroed
//   K2: counts[0..63] written unconditionally (incl. element 134217792)
//   K3: combine elements [1, 1+SEC) = final values; dispatch 1.0s; out[0]=l_aux

#define GEMM_BLOCKS 256   // 32 tokens x 64 experts (R17-verified MFMA math)
#define FILL_BLOCKS 1792
#define B0 16777217u
#define CH 9363u          // ceil(16777231 / FILL_BLOCKS)
#define N4END 33554448u
#define WSCALE 4096.0f
#define INV_WSCALE (1.0f / 4096.0f)

typedef float f32x4 __attribute__((ext_vector_type(4)));
typedef _Float16 f16x8 __attribute__((ext_vector_type(8)));

// direct global->LDS DMA, 16B per lane (dst = uniform base + lane*16)
#define GLOAD(G, L) __builtin_amdgcn_global_load_lds(                          \
    (const __attribute__((address_space(1))) void*)(G),                        \
    (__attribute__((address_space(3))) void*)(L), 16, 0, 0)

// raw barrier: LDS-ordered only; global loads stay in flight (T3/T4)
#define RAWBAR                                                                 \
    asm volatile("s_waitcnt lgkmcnt(0)" ::: "memory");                         \
    __builtin_amdgcn_sched_barrier(0);                                         \
    __builtin_amdgcn_s_barrier();                                              \
    __builtin_amdgcn_sched_barrier(0);

// 8 fp32 (two float4) -> f16 hi/lo vectors (read-side conversion)
#define CVT8(H, L, V0, V1, SC) do { float t_;                                  \
    t_ = (V0).x * (SC); H[0] = (_Float16)t_; L[0] = (_Float16)(t_ - (float)H[0]); \
    t_ = (V0).y * (SC); H[1] = (_Float16)t_; L[1] = (_Float16)(t_ - (float)H[1]); \
    t_ = (V0).z * (SC); H[2] = (_Float16)t_; L[2] = (_Float16)(t_ - (float)H[2]); \
    t_ = (V0).w * (SC); H[3] = (_Float16)t_; L[3] = (_Float16)(t_ - (float)H[3]); \
    t_ = (V1).x * (SC); H[4] = (_Float16)t_; L[4] = (_Float16)(t_ - (float)H[4]); \
    t_ = (V1).y * (SC); H[5] = (_Float16)t_; L[5] = (_Float16)(t_ - (float)H[5]); \
    t_ = (V1).z * (SC); H[6] = (_Float16)t_; L[6] = (_Float16)(t_ - (float)H[6]); \
    t_ = (V1).w * (SC); H[7] = (_Float16)t_; L[7] = (_Float16)(t_ - (float)H[7]); \
} while (0)

// ---------------- K1: gload_lds MFMA GEMM + dispatch-half fill ---------------
// R21 structure; ONE mechanism changed: GEMM staging is global_load_lds
// (fp32 straight to LDS, no VGPR round-trip), counted vmcnt(3) + raw barriers
// keep next-next-chunk loads in flight ACROSS barriers; f16 hi/lo conversion
// moved to read side (identical math). LDS layout XOR-swizzled BOTH sides
// (rule #21): slot c of row r lives at phys c^((r&7)<<1) — global source is
// pre-swizzled at issue, ds_reads apply the same involution.
__global__ __launch_bounds__(512) void k_main(const float* __restrict__ x,
                                              const float* __restrict__ w,
                                              float* __restrict__ gate,
                                              int* __restrict__ idx,
                                              float* __restrict__ me_part,
                                              int* __restrict__ cnt_g,
                                              float* __restrict__ la_ws,
                                              float* __restrict__ out) {
    int bid = blockIdx.x;
    int tid = threadIdx.x;
    if (bid < GEMM_BLOCKS) {
        __shared__ float Af[2][32 * 64];   // 16 KB (linear, swizzled cols)
        __shared__ float Wf[2][64 * 64];   // 32 KB
        __shared__ float Sl[32][66];       // 8.4 KB
        __shared__ float sm[32];
        __shared__ float sinv[32];
        __shared__ int sidx[32];
        int t0 = bid * 32;
        int wv = tid >> 6;                 // wave 0..7
        int l = tid & 63;

        // ---- staging slot ownership (slot = 16B = 4 fp32) ----
        // A: 512 slots; thread owns slot tid: row tid>>4, phys col tid&15,
        // logical col = phys ^ ((row&7)<<1)  (involution)
        int sar = tid >> 4;
        int sacl = (tid & 15) ^ ((sar & 7) << 1);
        const float* aga = x + (size_t)(t0 + sar) * Dm + sacl * 4;
        // W: 1024 slots; thread owns slots tid and tid+512
        int w1r = tid >> 4;
        int w1cl = (tid & 15) ^ ((w1r & 7) << 1);
        int w2r = 32 + (tid >> 4);
        int w2cl = (tid & 15) ^ ((w2r & 7) << 1);
        const float* wg1 = w + (size_t)w1r * Dm + w1cl * 4;
        const float* wg2 = w + (size_t)w2r * Dm + w2cl * 4;

        // ---- MFMA mapping (R17-verified): wave wv -> (mt = wv&1, nt = wv>>1)
        int lr = l & 15;
        int lg = l >> 4;
        int mt = wv & 1;
        int nt = wv >> 1;
        int ra = mt * 16 + lr;             // A row
        int rw = nt * 16 + lr;             // W row
        int mrow = (lr & 7) << 1;          // read-side XOR (ra&7 == rw&7 == lr&7)
        f32x4 acc = {0.f, 0.f, 0.f, 0.f};

#define ISSUE(B, KB)                                                           \
        GLOAD(aga + (KB), &Af[B][wv * 256]);                                   \
        GLOAD(wg1 + (KB), &Wf[B][wv * 256]);                                   \
        GLOAD(wg2 + (KB), &Wf[B][2048 + wv * 256]);

        ISSUE(0, 0)
        ISSUE(1, 64)
        asm volatile("s_waitcnt vmcnt(3)" ::: "memory");   // buf0 landed
        __builtin_amdgcn_sched_barrier(0);
        __builtin_amdgcn_s_barrier();
        __builtin_amdgcn_sched_barrier(0);

        for (int ch = 0; ch < 16; ++ch) {
            int B = ch & 1;
            // compute chunk ch from buf B (fp32 LDS -> f16 hi/lo -> MFMA)
#pragma unroll
            for (int ks = 0; ks < 2; ++ks) {
                int cp = (ks * 8 + lg * 2) ^ mrow;   // phys slot (pair stays adjacent)
                const float4* Ap = (const float4*)&Af[B][(size_t)ra * 64 + cp * 4];
                float4 a0 = Ap[0], a1 = Ap[1];
                const float4* Wp = (const float4*)&Wf[B][(size_t)rw * 64 + cp * 4];
                float4 b0 = Wp[0], b1 = Wp[1];
                f16x8 ah, al2, bh, bl;
                CVT8(ah, al2, a0, a1, 1.0f);
                CVT8(bh, bl, b0, b1, WSCALE);
                acc = __builtin_amdgcn_mfma_f32_16x16x32_f16(ah, bh, acc, 0, 0, 0);
                acc = __builtin_amdgcn_mfma_f32_16x16x32_f16(al2, bh, acc, 0, 0, 0);
                acc = __builtin_amdgcn_mfma_f32_16x16x32_f16(ah, bl, acc, 0, 0, 0);
            }
            RAWBAR                          // all waves done reading buf B
            if (ch + 2 < 16) { ISSUE(B, (ch + 2) * 64) }
            if (ch + 1 < 16) {
                if (ch + 2 < 16) {
                    asm volatile("s_waitcnt vmcnt(3)" ::: "memory");  // ch+1 landed
                } else {
                    asm volatile("s_waitcnt vmcnt(0)" ::: "memory");
                }
            }
            RAWBAR                          // buf B^1 visible to all waves
        }
#undef ISSUE
        __syncthreads();
        // D -> Sl (R16/R17-verified C/D layout: row = lg*4 + r, col = lr)
#pragma unroll
        for (int r = 0; r < 4; ++r)
            Sl[mt * 16 + lg * 4 + r][nt * 16 + lr] = acc[r] * INV_WSCALE;
        __syncthreads();
        if (tid < 32) {   // row phase: first-index argmax + exp-sum
            float m = Sl[tid][0];
            int am = 0;
#pragma unroll
            for (int c = 1; c < E; ++c) {
                float v = Sl[tid][c];
                if (v > m) { m = v; am = c; }
            }
            float ssum = 0.f;
#pragma unroll
            for (int c = 0; c < E; ++c) ssum += __expf(Sl[tid][c] - m);
            float inv = 1.0f / ssum;
            gate[t0 + tid] = inv;
            idx[t0 + tid] = am;
            sm[tid] = m;
            sinv[tid] = inv;
            sidx[tid] = am;
        }
        __syncthreads();
        if (tid < E) {    // column phase: me partials + exact expert histogram
            float cs = 0.f;
            int cnt = 0;
#pragma unroll 8
            for (int r = 0; r < 32; ++r) {
                cs += __expf(Sl[r][tid] - sm[r]) * sinv[r];
                cnt += (sidx[r] == tid) ? 1 : 0;
            }
            me_part[bid * E + tid] = cs;
            cnt_g[bid * E + tid] = cnt;
        }
    } else {
        // block-chunked zero-fill of dispatch half + counts[0..62]
        int fb = bid - GEMM_BLOCKS;
        if (fb == 0 && tid == 0) {
            out[1 + SEC] = 0.f; out[2 + SEC] = 0.f; out[3 + SEC] = 0.f;
            la_ws[0] = 0.f;
        }
        unsigned base = B0 + (unsigned)fb * CH;
        f32x4 z = {0.f, 0.f, 0.f, 0.f};
        f32x4* o4 = (f32x4*)out;
        for (unsigned j = tid; j < CH; j += 512u) {
            unsigned i = base + j;
            if (i < N4END) o4[i] = z;
        }
    }
}

// ---------------- K2: quartered scan -> tg[], counts, l_aux accum ------------
// R21's proven kernel (256 GEMM blocks), verbatim.
__global__ __launch_bounds__(256) void k_scan(const int* __restrict__ idx,
                                              const float* __restrict__ gate,
                                              const float* __restrict__ me_part,
                                              const int* __restrict__ cnt_g,
                                              float2* __restrict__ tg,
                                              float* __restrict__ la_ws,
                                              float* __restrict__ out) {
    int e = blockIdx.x >> 2;
    int q = blockIdx.x & 3;
    int tid = threadIdx.x;
    int lane = tid & 63;
    int wid = tid >> 6;
    __shared__ int wsum[4];
    __shared__ int ired[256];
    __shared__ float red[256];
    int nb = q << 6;
    int a = 0;
    for (int b = tid; b < nb; b += 256) a += cnt_g[b * E + e];
    ired[tid] = a;
    __syncthreads();
    for (int s2 = 128; s2 > 0; s2 >>= 1) {
        if (tid < s2) ired[tid] += ired[tid + s2];
        __syncthreads();
    }
    int running = ired[0];
    __syncthreads();
    for (int ch = 0; ch < 8; ++ch) {
        int t = q * 2048 + ch * 256 + tid;
        bool f = (idx[t] == e);
        unsigned long long b = __ballot(f);
        int pre = __popcll(b & ((1ull << lane) - 1ull));
        if (lane == 0) wsum[wid] = __popcll(b);
        __syncthreads();
        int off = running;
#pragma unroll
        for (int w2 = 0; w2 < 4; ++w2)
            if (w2 < wid) off += wsum[w2];
        int p = off + pre;
        if (f) {
            int tgt = (p < CAP) ? e * CAP + p : -1;
            tg[t] = make_float2(__int_as_float(tgt), gate[t]);
        }
        running += wsum[0] + wsum[1] + wsum[2] + wsum[3];
        __syncthreads();
    }
    if (q == 3) {
        red[tid] = me_part[tid * E + e];
        __syncthreads();
        for (int s2 = 128; s2 > 0; s2 >>= 1) {
            if (tid < s2) red[tid] += red[tid + s2];
            __syncthreads();
        }
        if (tid == 0) {
            out[1 + 2 * (size_t)SEC + e] = (float)running;   // exp_counts
            float la = red[0] * (1.0f / (float)S) *
                       ((float)running / (float)S) * (float)E;
            atomicAdd(la_ws, la);
        }
    }
}

// ---------------- K3: merge-fill combine half + dispatch ones + l_aux --------
// R21's proven pure-write merge kernel, verbatim.
__global__ __launch_bounds__(256) void k_merge(const float2* __restrict__ tg,
                                               const float* __restrict__ la_ws,
                                               float* __restrict__ out) {
    int bid = blockIdx.x;
    int tid = threadIdx.x;
    if (bid == 0 && tid == 0) out[0] = la_ws[0];   // l_aux (K2 complete)
    f32x4* o4 = (f32x4*)out;
#pragma unroll
    for (int k = 0; k < 4; ++k) {
        int t = bid * 4 + k;
        float2 g = tg[t];
        int tgt = __float_as_int(g.x);     // local slot in [0,8192) or -1
        float gv = g.y;
        for (int j = 1 + tid; j < 2048; j += 256) {
            int base = 4 * j - 1;
            f32x4 v;
            v[0] = (tgt == base) ? gv : 0.f;
            v[1] = (tgt == base + 1) ? gv : 0.f;
            v[2] = (tgt == base + 2) ? gv : 0.f;
            v[3] = (tgt == base + 3) ? gv : 0.f;
            o4[2048u * (unsigned)t + (unsigned)j] = v;
        }
        if (tid < 4) {   // boundary scalars: local c = 0,1,2,8191
            int c = (tid < 3) ? tid : 8191;
            out[1 + (size_t)t * 8192 + c] = (tgt == c) ? gv : 0.f;
        }
        if (tid == 4 && tgt >= 0)   // dispatch one (half zeroed by K1)
            out[1 + SEC + (size_t)t * 8192 + tgt] = 1.0f;
    }
}

extern "C" void kernel_launch(void* const* d_in, const int* in_sizes, int n_in,
                              void* d_out, int out_size, void* d_ws, size_t ws_size,
                              hipStream_t stream) {
    const float* x = (const float*)d_in[0];      // [S, Dm] fp32
    const float* w = (const float*)d_in[1];      // [E, Dm] fp32
    float* out = (float*)d_out;

    // ws layout
    float* me_part = (float*)d_ws;               // [256][64] = 64 KB
    float* gate = me_part + GEMM_BLOCKS * E;     // S floats
    int* idx = (int*)(gate + S);                 // S ints
    int* cnt_g = idx + S;                        // [256][64] = 64 KB
    float2* tg = (float2*)(cnt_g + GEMM_BLOCKS * E);   // S float2 = 64 KB
    float* la_ws = (float*)(tg + S);             // 1 float

    k_main<<<dim3(GEMM_BLOCKS + FILL_BLOCKS), dim3(512), 0, stream>>>(
        x, w, gate, idx, me_part, cnt_g, la_ws, out);
    k_scan<<<dim3(256), dim3(256), 0, stream>>>(
        idx, gate, me_part, cnt_g, tg, la_ws, out);
    k_merge<<<dim3(2048), dim3(256), 0, stream>>>(tg, la_ws, out);
}